// Round 7
// baseline (1101.054 us; speedup 1.0000x reference)
//
#include <hip/hip_runtime.h>
#include <math.h>

// GraphSage GNN forward. N=100000 (div 16), E=600000, HID=128, OUT=40, G=64, L=3.
// R7: barrier-free fused layer kernel. One wave owns 16 rows x 128 cols.
// W staged once per block in per-lane MFMA-frag LDS layout (conflict-free b128 reads).
// A frags (self + gathered neighbor mean) built in registers from global; no A-LDS,
// no per-tile syncs. Row L2-norm via 2 shfl_xor. BN col-stats = separate coalesced pass.

typedef __bf16 bf16;
typedef __bf16 bf16x4 __attribute__((ext_vector_type(4)));
typedef __bf16 bf16x8 __attribute__((ext_vector_type(8)));
typedef float  f32x4  __attribute__((ext_vector_type(4)));

static inline size_t alignup(size_t x){ return (x + 255) & ~(size_t)255; }

// ---------------- CSR build ----------------
__global__ void count_kernel(const int* __restrict__ ei, int E, int* __restrict__ cnt){
  int e = blockIdx.x*256 + threadIdx.x;
  if (e < E) atomicAdd(&cnt[ei[E + e]], 1);   // dst row
}

__global__ void scan1_kernel(const int* __restrict__ cnt, int* __restrict__ rs,
                             int* __restrict__ bsum, int N){
  __shared__ int s[256];
  int t = threadIdx.x;
  int i = blockIdx.x*256 + t;
  int v = (i < N) ? cnt[i] : 0;
  s[t] = v; __syncthreads();
  for (int off = 1; off < 256; off <<= 1){
    int x = (t >= off) ? s[t-off] : 0;
    __syncthreads();
    s[t] += x;
    __syncthreads();
  }
  if (i < N) rs[i] = s[t] - v;
  if (t == 255) bsum[blockIdx.x] = s[255];
}

__global__ void scan2_kernel(int* __restrict__ bsum, int NB){
  __shared__ int s[512];
  int t = threadIdx.x;
  int v = (t < NB) ? bsum[t] : 0;
  s[t] = v; __syncthreads();
  for (int off = 1; off < 512; off <<= 1){
    int x = (t >= off) ? s[t-off] : 0;
    __syncthreads();
    s[t] += x;
    __syncthreads();
  }
  if (t < NB) bsum[t] = s[t] - v;
}

__global__ void scan3_kernel(int* __restrict__ rs, const int* __restrict__ bsum,
                             int* __restrict__ cur, int N){
  int i = blockIdx.x*256 + threadIdx.x;
  if (i < N){
    int v = rs[i] + bsum[blockIdx.x];
    rs[i] = v;
    cur[i] = v;
  }
}

__global__ void fill_kernel(const int* __restrict__ ei, int E, int* __restrict__ cur,
                            int* __restrict__ esrc){
  int e = blockIdx.x*256 + threadIdx.x;
  if (e < E){
    int d = ei[E + e];
    int p = atomicAdd(&cur[d], 1);
    esrc[p] = ei[e];
  }
}

// ---------------- x -> bf16 ----------------
__global__ void xbf_kernel(const float* __restrict__ x, bf16* __restrict__ xb, int total8){
  int i = blockIdx.x*256 + threadIdx.x;
  if (i < total8){
    float4 a = *(const float4*)(x + (size_t)i*8);
    float4 b = *(const float4*)(x + (size_t)i*8 + 4);
    bf16x8 o;
    o[0]=(bf16)a.x; o[1]=(bf16)a.y; o[2]=(bf16)a.z; o[3]=(bf16)a.w;
    o[4]=(bf16)b.x; o[5]=(bf16)b.y; o[6]=(bf16)b.z; o[7]=(bf16)b.w;
    *(bf16x8*)(xb + (size_t)i*8) = o;
  }
}

// ---------------- collapsed postMP weights: Wc = W2@W1 (40x128), bc = W2@b1 + b2 ----------------
__global__ void wc_kernel(const float* __restrict__ W1, const float* __restrict__ b1,
                          const float* __restrict__ W2, const float* __restrict__ b2,
                          float* __restrict__ Wc, float* __restrict__ bc){
  int o = blockIdx.x;        // 0..39
  int k = threadIdx.x;       // 0..127
  float s = 0.0f;
  for (int j = 0; j < 128; ++j) s = fmaf(W2[o*128 + j], W1[j*128 + k], s);
  Wc[o*128 + k] = s;
  __shared__ float r[128];
  r[k] = W2[o*128 + k] * b1[k];
  __syncthreads();
  for (int off = 64; off; off >>= 1){
    if (k < off) r[k] += r[k + off];
    __syncthreads();
  }
  if (k == 0) bc[o] = r[0] + b2[o];
}

// ---------------- weight prep: Wbig[l][c][k], k<128 -> Wl[l][c][k], k>=128 -> Wr[l][c][k-128]
__global__ void wprep_kernel(const float* __restrict__ Wl, const float* __restrict__ Wr,
                             bf16* __restrict__ Wbig){
  int idx = blockIdx.x*256 + threadIdx.x;
  if (idx < 3*128*256){
    int l = idx / 32768, rem = idx % 32768, c = rem >> 8, k = rem & 255;
    float w = (k < 128) ? Wl[l*16384 + c*128 + k] : Wr[l*16384 + c*128 + (k-128)];
    Wbig[idx] = (bf16)w;
  }
}

// ---------------- fused barrier-free layer kernel ----------------
// Wave owns 16 rows x 128 cols. Per row: A = [act(h_row) | mean_j act(h_j)], K=256.
// Lane (quad,l16): row = rbase+l16; A-frag k-chunk = ks*32+quad*8; C cols nt*16+quad*4+r.
__global__ __launch_bounds__(256, 2) void layer_kernel(
    const bf16* __restrict__ hin, const float* __restrict__ bnp, int use_act,
    const bf16* __restrict__ Wbig, const float* __restrict__ bl, const float* __restrict__ br,
    const int* __restrict__ rs, const int* __restrict__ cnt, const int* __restrict__ esrc,
    bf16* __restrict__ hout, int N)
{
  __shared__ bf16 wlds[64*64*8];   // 64 frags (nt*8+ks) x 64 lanes x 8 bf16 = 64 KB
  const int t = threadIdx.x;
  // stage W into per-lane frag layout: frag(nt,ks) lane(quad,l16) = Wbig[nt*16+l16][ks*32+quad*8..+7]
  for (int g = t; g < 4096; g += 256){
    int c = g >> 5, kc = g & 31;                 // c = W row (output col), kc = 16B chunk of k
    int nt = c >> 4, l16c = c & 15, ks = kc >> 2, qd = kc & 3;
    bf16x8 v = *(const bf16x8*)(Wbig + (size_t)c*256 + kc*8);
    *(bf16x8*)(wlds + (((nt*8 + ks)*64) + qd*16 + l16c)*8) = v;
  }
  __syncthreads();   // only sync in the kernel

  const int lane = t & 63;
  const int quad = lane >> 4, l16 = lane & 15;

  // act params for this lane's 4 k-chunks (hin cols ks*32+quad*8..+7); shared by self & gather
  float sc[4][8], sh[4][8];
  if (use_act){
    #pragma unroll
    for (int ks = 0; ks < 4; ++ks){
      *(float4*)(sc[ks])   = *(const float4*)(bnp + ks*32 + quad*8);
      *(float4*)(sc[ks]+4) = *(const float4*)(bnp + ks*32 + quad*8 + 4);
      *(float4*)(sh[ks])   = *(const float4*)(bnp + 128 + ks*32 + quad*8);
      *(float4*)(sh[ks]+4) = *(const float4*)(bnp + 128 + ks*32 + quad*8 + 4);
    }
  }

  const int ntiles = N >> 4;   // 16 rows per wave-tile; N % 16 == 0
  const int gwave  = (blockIdx.x*256 + t) >> 6;
  const int nwaves = (gridDim.x*256) >> 6;
  for (int tile = gwave; tile < ntiles; tile += nwaves){
    const int row = (tile << 4) + l16;
    const int start = rs[row];
    const int deg = cnt[row];
    // ---- self A-frags ----
    bf16x8 selfv[4];
    #pragma unroll
    for (int ks = 0; ks < 4; ++ks)
      selfv[ks] = *(const bf16x8*)(hin + (size_t)row*128 + ks*32 + quad*8);
    if (use_act){
      #pragma unroll
      for (int ks = 0; ks < 4; ++ks)
        #pragma unroll
        for (int j = 0; j < 8; ++j)
          selfv[ks][j] = (bf16)fmaxf(fmaf((float)selfv[ks][j], sc[ks][j], sh[ks][j]), 0.0f);
    }
    // ---- gather neighbor mean (per-lane CSR walk, 4-edge unroll for ILP) ----
    float ag[4][8];
    #pragma unroll
    for (int ks = 0; ks < 4; ++ks)
      #pragma unroll
      for (int j = 0; j < 8; ++j) ag[ks][j] = 0.f;
    int e = 0;
    for (; e + 4 <= deg; e += 4){
      int s0 = esrc[start + e],     s1 = esrc[start + e + 1];
      int s2 = esrc[start + e + 2], s3 = esrc[start + e + 3];
      bf16x8 u0[4], u1[4], u2[4], u3[4];
      #pragma unroll
      for (int ks = 0; ks < 4; ++ks){
        u0[ks] = *(const bf16x8*)(hin + (size_t)s0*128 + ks*32 + quad*8);
        u1[ks] = *(const bf16x8*)(hin + (size_t)s1*128 + ks*32 + quad*8);
        u2[ks] = *(const bf16x8*)(hin + (size_t)s2*128 + ks*32 + quad*8);
        u3[ks] = *(const bf16x8*)(hin + (size_t)s3*128 + ks*32 + quad*8);
      }
      if (use_act){
        #pragma unroll
        for (int ks = 0; ks < 4; ++ks)
          #pragma unroll
          for (int j = 0; j < 8; ++j)
            ag[ks][j] += fmaxf(fmaf((float)u0[ks][j], sc[ks][j], sh[ks][j]), 0.f)
                       + fmaxf(fmaf((float)u1[ks][j], sc[ks][j], sh[ks][j]), 0.f)
                       + fmaxf(fmaf((float)u2[ks][j], sc[ks][j], sh[ks][j]), 0.f)
                       + fmaxf(fmaf((float)u3[ks][j], sc[ks][j], sh[ks][j]), 0.f);
      } else {
        #pragma unroll
        for (int ks = 0; ks < 4; ++ks)
          #pragma unroll
          for (int j = 0; j < 8; ++j)
            ag[ks][j] += (float)u0[ks][j] + (float)u1[ks][j]
                       + (float)u2[ks][j] + (float)u3[ks][j];
      }
    }
    for (; e < deg; ++e){
      int s0 = esrc[start + e];
      bf16x8 u0[4];
      #pragma unroll
      for (int ks = 0; ks < 4; ++ks)
        u0[ks] = *(const bf16x8*)(hin + (size_t)s0*128 + ks*32 + quad*8);
      if (use_act){
        #pragma unroll
        for (int ks = 0; ks < 4; ++ks)
          #pragma unroll
          for (int j = 0; j < 8; ++j)
            ag[ks][j] += fmaxf(fmaf((float)u0[ks][j], sc[ks][j], sh[ks][j]), 0.f);
      } else {
        #pragma unroll
        for (int ks = 0; ks < 4; ++ks)
          #pragma unroll
          for (int j = 0; j < 8; ++j) ag[ks][j] += (float)u0[ks][j];
      }
    }
    const float inv = 1.0f / (float)max(deg, 1);
    bf16x8 aggv[4];
    #pragma unroll
    for (int ks = 0; ks < 4; ++ks)
      #pragma unroll
      for (int j = 0; j < 8; ++j) aggv[ks][j] = (bf16)(ag[ks][j] * inv);
    // ---- MFMA: 8 n-tiles, K=256 ----
    f32x4 acc[8];
    #pragma unroll
    for (int nt = 0; nt < 8; ++nt)
      #pragma unroll
      for (int r = 0; r < 4; ++r) acc[nt][r] = 0.f;
    #pragma unroll
    for (int ks = 0; ks < 8; ++ks){
      bf16x8 af = (ks < 4) ? selfv[ks] : aggv[ks - 4];
      #pragma unroll
      for (int nt = 0; nt < 8; ++nt){
        bf16x8 wf = *(const bf16x8*)(wlds + (((nt*8 + ks)*64) + lane)*8);
        acc[nt] = __builtin_amdgcn_mfma_f32_16x16x32_bf16(wf, af, acc[nt], 0, 0, 0);
      }
    }
    // ---- epilogue: bias (+deg-0 fix), row L2-norm (in-wave), store bf16 ----
    float rsq = 0.f;
    #pragma unroll
    for (int nt = 0; nt < 8; ++nt){
      float4 bl4 = *(const float4*)(bl + nt*16 + quad*4);
      float4 br4 = *(const float4*)(br + nt*16 + quad*4);
      float b0 = bl4.x + (deg ? br4.x : 0.f);
      float b1 = bl4.y + (deg ? br4.y : 0.f);
      float b2 = bl4.z + (deg ? br4.z : 0.f);
      float b3 = bl4.w + (deg ? br4.w : 0.f);
      acc[nt][0] += b0; acc[nt][1] += b1; acc[nt][2] += b2; acc[nt][3] += b3;
      rsq += acc[nt][0]*acc[nt][0] + acc[nt][1]*acc[nt][1]
           + acc[nt][2]*acc[nt][2] + acc[nt][3]*acc[nt][3];
    }
    rsq += __shfl_xor(rsq, 16);
    rsq += __shfl_xor(rsq, 32);
    const float scl = 1.0f / fmaxf(sqrtf(rsq), 1e-12f);
    #pragma unroll
    for (int nt = 0; nt < 8; ++nt){
      bf16x4 o;
      o[0] = (bf16)(acc[nt][0]*scl); o[1] = (bf16)(acc[nt][1]*scl);
      o[2] = (bf16)(acc[nt][2]*scl); o[3] = (bf16)(acc[nt][3]*scl);
      *(bf16x4*)(hout + (size_t)row*128 + nt*16 + quad*4) = o;
    }
  }
}

// ---------------- column stats of hout (coalesced): colstats += [colsum|colsq] ----------------
__global__ __launch_bounds__(256) void colstats_kernel(
    const bf16* __restrict__ h, float* __restrict__ colstats, int N)
{
  __shared__ float red[256][8];
  const int t = threadIdx.x;
  const int cg = t & 15;    // cols cg*8 .. +7
  const int rl = t >> 4;    // 16 row-lanes
  float s[8], q[8];
  #pragma unroll
  for (int j = 0; j < 8; ++j){ s[j] = 0.f; q[j] = 0.f; }
  for (int n = blockIdx.x*16 + rl; n < N; n += gridDim.x*16){
    bf16x8 v = *(const bf16x8*)(h + (size_t)n*128 + cg*8);
    #pragma unroll
    for (int j = 0; j < 8; ++j){
      float x = (float)v[j];
      s[j] += x; q[j] += x*x;
    }
  }
  #pragma unroll
  for (int j = 0; j < 8; ++j) red[t][j] = s[j];
  __syncthreads();
  if (t < 128){
    float a = 0.f;
    #pragma unroll
    for (int r = 0; r < 16; ++r) a += red[r*16 + (t>>3)][t & 7];
    atomicAdd(&colstats[t], a);
  }
  __syncthreads();
  #pragma unroll
  for (int j = 0; j < 8; ++j) red[t][j] = q[j];
  __syncthreads();
  if (t < 128){
    float a = 0.f;
    #pragma unroll
    for (int r = 0; r < 16; ++r) a += red[r*16 + (t>>3)][t & 7];
    atomicAdd(&colstats[128 + t], a);
  }
}

// ---------------- BN params; zero stats for next layer ----------------
__global__ void bn_params_kernel(float* __restrict__ cs, const float* __restrict__ gamma,
                                 const float* __restrict__ beta, float* __restrict__ bnp, float Nf){
  int t = threadIdx.x;   // 0..127
  float sum = cs[t], sq = cs[128 + t];
  float mu  = sum / Nf;
  float var = fmaxf(sq / Nf - mu*mu, 0.0f);
  float inv = rsqrtf(var + 1e-5f);
  float scale = gamma[t] * inv;
  bnp[t] = scale;
  bnp[128 + t] = beta[t] - mu * scale;
  cs[t] = 0.0f; cs[128 + t] = 0.0f;
}

// ---------------- pool act(h) per graph ----------------
__global__ __launch_bounds__(256) void poolh_kernel(
    const bf16* __restrict__ h, const float* __restrict__ bnp,
    const int* __restrict__ batch, float* __restrict__ pooledh, int N)
{
  const int t = threadIdx.x;
  const int col = t & 127;
  const int half = t >> 7;
  const float sc = bnp[col];
  const float sh = bnp[128 + col];
  const int chunk = (N + gridDim.x - 1) / gridDim.x;
  const int lo = blockIdx.x * chunk;
  const int hi = min(N, lo + chunk);
  if (lo >= hi) return;
  int gcur = -1;
  float acc = 0.f;
  for (int n = lo + half; n < hi; n += 2){
    int g = batch[n];
    if (g != gcur){
      if (gcur >= 0) atomicAdd(&pooledh[gcur*128 + col], acc);
      gcur = g; acc = 0.f;
    }
    float v = (float)h[(size_t)n*128 + col];
    acc += fmaxf(fmaf(v, sc, sh), 0.f);
  }
  if (gcur >= 0) atomicAdd(&pooledh[gcur*128 + col], acc);
}

// ---------------- final: out[g] = log_softmax(pooledh[g] @ Wc^T + cnt_g*bc) ----------------
__global__ void lsm_kernel(const float* __restrict__ ph, const float* __restrict__ Wc,
                           const float* __restrict__ bc, const int* __restrict__ batch,
                           int N, float* __restrict__ out)
{
  __shared__ int cntg_s;
  const int g = blockIdx.x;
  const int t = threadIdx.x;   // 64 threads = one wave
  if (t == 0){
    int lo = 0, hi = N;
    while (lo < hi){ int mid = (lo + hi) >> 1; if (batch[mid] < g) lo = mid + 1; else hi = mid; }
    int lo2 = lo, hi2 = N;
    while (lo2 < hi2){ int mid = (lo2 + hi2) >> 1; if (batch[mid] < g + 1) lo2 = mid + 1; else hi2 = mid; }
    cntg_s = lo2 - lo;
  }
  __syncthreads();
  float z = -3.0e38f;
  if (t < 40){
    float s = (float)cntg_s * bc[t];
    const float* phg = ph + g*128;
    const float* w = Wc + t*128;
    for (int k = 0; k < 128; k += 4){
      float4 a = *(const float4*)(phg + k);
      float4 b = *(const float4*)(w + k);
      s = fmaf(a.x, b.x, s); s = fmaf(a.y, b.y, s);
      s = fmaf(a.z, b.z, s); s = fmaf(a.w, b.w, s);
    }
    z = s;
  }
  float mx = z;
  #pragma unroll
  for (int off = 32; off; off >>= 1) mx = fmaxf(mx, __shfl_xor(mx, off));
  float ex = (t < 40) ? expf(z - mx) : 0.0f;
  float sum = ex;
  #pragma unroll
  for (int off = 32; off; off >>= 1) sum += __shfl_xor(sum, off);
  float lse = mx + logf(sum);
  if (t < 40) out[g*40 + t] = z - lse;
}

extern "C" void kernel_launch(void* const* d_in, const int* in_sizes, int n_in,
                              void* d_out, int out_size, void* d_ws, size_t ws_size,
                              hipStream_t stream)
{
  const float* x    = (const float*)d_in[0];
  const int*   ei   = (const int*)d_in[1];
  const int*   batch= (const int*)d_in[2];
  const float* Wl   = (const float*)d_in[3];
  const float* bl   = (const float*)d_in[4];
  const float* Wr   = (const float*)d_in[5];
  const float* br   = (const float*)d_in[6];
  const float* gamma= (const float*)d_in[7];
  const float* beta = (const float*)d_in[8];
  const float* W1   = (const float*)d_in[9];
  const float* b1   = (const float*)d_in[10];
  const float* W2   = (const float*)d_in[11];
  const float* b2   = (const float*)d_in[12];
  float* out = (float*)d_out;

  const int N = in_sizes[0] / 128;
  const int E = in_sizes[1] / 2;
  const int G = out_size / 40;

  char* p = (char*)d_ws;
  auto carve = [&](size_t bytes)->char*{ char* r = p; p += alignup(bytes); return r; };
  bf16*  xbf      = (bf16*)carve((size_t)N * 128 * 2);
  bf16*  hA       = (bf16*)carve((size_t)N * 128 * 2);
  bf16*  hB       = (bf16*)carve((size_t)N * 128 * 2);
  int*   esrc     = (int*)carve((size_t)E * 4);
  int*   rs       = (int*)carve((size_t)N * 4);
  int*   cnt      = (int*)carve((size_t)N * 4);
  int*   cur      = (int*)carve((size_t)N * 4);
  int*   bsum     = (int*)carve(512 * 4);
  float* colstats = (float*)carve(256 * 4);
  float* bnp      = (float*)carve(256 * 4);
  float* Wc       = (float*)carve(40 * 128 * 4);
  float* bc       = (float*)carve(40 * 4);
  bf16*  Wbig     = (bf16*)carve((size_t)3 * 128 * 256 * 2);
  float* pooledh  = (float*)carve((size_t)G * 128 * 4);

  hipMemsetAsync(cnt, 0, (size_t)N * 4, stream);
  hipMemsetAsync(colstats, 0, 256 * 4, stream);
  hipMemsetAsync(pooledh, 0, (size_t)G * 128 * 4, stream);

  const int eb = (E + 255) / 256;
  const int nb = (N + 255) / 256;
  count_kernel<<<eb, 256, 0, stream>>>(ei, E, cnt);
  scan1_kernel<<<nb, 256, 0, stream>>>(cnt, rs, bsum, N);
  scan2_kernel<<<1, 512, 0, stream>>>(bsum, nb);
  scan3_kernel<<<nb, 256, 0, stream>>>(rs, bsum, cur, N);
  fill_kernel<<<eb, 256, 0, stream>>>(ei, E, cur, esrc);
  xbf_kernel<<<(N*16 + 255)/256, 256, 0, stream>>>(x, xbf, N*16);
  wc_kernel<<<40, 128, 0, stream>>>(W1, b1, W2, b2, Wc, bc);
  wprep_kernel<<<(3*128*256 + 255)/256, 256, 0, stream>>>(Wl, Wr, Wbig);

  const float Nf = (float)N;
  // ping-pong: l0 xbf->hA, l1 hA->hB, l2 hB->hA  (hin never aliases hout)
  const bf16* ins[3]  = {xbf, hA, hB};
  bf16*       outs[3] = {hA,  hB, hA};
  for (int l = 0; l < 3; ++l){
    layer_kernel<<<512, 256, 0, stream>>>(ins[l], bnp, (l > 0) ? 1 : 0,
                                          Wbig + (size_t)l * 32768, bl + l*128, br + l*128,
                                          rs, cnt, esrc, outs[l], N);
    colstats_kernel<<<256, 256, 0, stream>>>(outs[l], colstats, N);
    bn_params_kernel<<<1, 128, 0, stream>>>(colstats, gamma + l*128, beta + l*128, bnp, Nf);
  }
  poolh_kernel<<<1024, 256, 0, stream>>>(hA, bnp, batch, pooledh, N);
  lsm_kernel<<<G, 64, 0, stream>>>(pooledh, Wc, bc, batch, N, out);
}

// Round 8
// 683.778 us; speedup vs baseline: 1.6103x; 1.6103x over previous
//
#include <hip/hip_runtime.h>
#include <math.h>

// GraphSage GNN forward. N=100000 (div 16/32), E=600000, HID=128, OUT=40, G=64, L=3.
// R8: R4 split (separate gather) + barrier-free row-wave GEMM (W in frag-LDS, one sync,
// in-wave L2-norm, direct coalescing-friendly streams). Lesson from R7: never mix the
// random gather with partial-line stores in one kernel (L2 thrash -> 10x write amp).

typedef __bf16 bf16;
typedef __bf16 bf16x4 __attribute__((ext_vector_type(4)));
typedef __bf16 bf16x8 __attribute__((ext_vector_type(8)));
typedef float  f32x4  __attribute__((ext_vector_type(4)));

static inline size_t alignup(size_t x){ return (x + 255) & ~(size_t)255; }

// ---------------- CSR build ----------------
__global__ void count_kernel(const int* __restrict__ ei, int E, int* __restrict__ cnt){
  int e = blockIdx.x*256 + threadIdx.x;
  if (e < E) atomicAdd(&cnt[ei[E + e]], 1);   // dst row
}

__global__ void scan1_kernel(const int* __restrict__ cnt, int* __restrict__ rs,
                             int* __restrict__ bsum, int N){
  __shared__ int s[256];
  int t = threadIdx.x;
  int i = blockIdx.x*256 + t;
  int v = (i < N) ? cnt[i] : 0;
  s[t] = v; __syncthreads();
  for (int off = 1; off < 256; off <<= 1){
    int x = (t >= off) ? s[t-off] : 0;
    __syncthreads();
    s[t] += x;
    __syncthreads();
  }
  if (i < N) rs[i] = s[t] - v;
  if (t == 255) bsum[blockIdx.x] = s[255];
}

__global__ void scan2_kernel(int* __restrict__ bsum, int NB){
  __shared__ int s[512];
  int t = threadIdx.x;
  int v = (t < NB) ? bsum[t] : 0;
  s[t] = v; __syncthreads();
  for (int off = 1; off < 512; off <<= 1){
    int x = (t >= off) ? s[t-off] : 0;
    __syncthreads();
    s[t] += x;
    __syncthreads();
  }
  if (t < NB) bsum[t] = s[t] - v;
}

__global__ void scan3_kernel(int* __restrict__ rs, const int* __restrict__ bsum,
                             int* __restrict__ cur, int N){
  int i = blockIdx.x*256 + threadIdx.x;
  if (i < N){
    int v = rs[i] + bsum[blockIdx.x];
    rs[i] = v;
    cur[i] = v;
  }
}

__global__ void fill_kernel(const int* __restrict__ ei, int E, int* __restrict__ cur,
                            int* __restrict__ esrc){
  int e = blockIdx.x*256 + threadIdx.x;
  if (e < E){
    int d = ei[E + e];
    int p = atomicAdd(&cur[d], 1);
    esrc[p] = ei[e];
  }
}

// ---------------- x -> bf16 ----------------
__global__ void xbf_kernel(const float* __restrict__ x, bf16* __restrict__ xb, int total8){
  int i = blockIdx.x*256 + threadIdx.x;
  if (i < total8){
    float4 a = *(const float4*)(x + (size_t)i*8);
    float4 b = *(const float4*)(x + (size_t)i*8 + 4);
    bf16x8 o;
    o[0]=(bf16)a.x; o[1]=(bf16)a.y; o[2]=(bf16)a.z; o[3]=(bf16)a.w;
    o[4]=(bf16)b.x; o[5]=(bf16)b.y; o[6]=(bf16)b.z; o[7]=(bf16)b.w;
    *(bf16x8*)(xb + (size_t)i*8) = o;
  }
}

// ---------------- collapsed postMP weights: Wc = W2@W1 (40x128), bc = W2@b1 + b2 ----------------
__global__ void wc_kernel(const float* __restrict__ W1, const float* __restrict__ b1,
                          const float* __restrict__ W2, const float* __restrict__ b2,
                          float* __restrict__ Wc, float* __restrict__ bc){
  int o = blockIdx.x;        // 0..39
  int k = threadIdx.x;       // 0..127
  float s = 0.0f;
  for (int j = 0; j < 128; ++j) s = fmaf(W2[o*128 + j], W1[j*128 + k], s);
  Wc[o*128 + k] = s;
  __shared__ float r[128];
  r[k] = W2[o*128 + k] * b1[k];
  __syncthreads();
  for (int off = 64; off; off >>= 1){
    if (k < off) r[k] += r[k + off];
    __syncthreads();
  }
  if (k == 0) bc[o] = r[0] + b2[o];
}

// ---------------- weight prep: Wbig[l][c][k], k<128 -> Wl[l][c][k], k>=128 -> Wr[l][c][k-128]
__global__ void wprep_kernel(const float* __restrict__ Wl, const float* __restrict__ Wr,
                             bf16* __restrict__ Wbig){
  int idx = blockIdx.x*256 + threadIdx.x;
  if (idx < 3*128*256){
    int l = idx / 32768, rem = idx % 32768, c = rem >> 8, k = rem & 255;
    float w = (k < 128) ? Wl[l*16384 + c*128 + k] : Wr[l*16384 + c*128 + (k-128)];
    Wbig[idx] = (bf16)w;
  }
}

// ---------------- gather: aggx[n] = mean_{j in N(n)} act(h[j]); act = relu(sc*h+sh) if use_act
// 4 nodes per wave, 16 lanes x 16B (bf16x8) per gathered row.  (R4's measured-best shape.)
__global__ __launch_bounds__(256) void gather_kernel(
    const bf16* __restrict__ hsrc, const float* __restrict__ bnp, int use_act,
    const int* __restrict__ rs, const int* __restrict__ cnt, const int* __restrict__ esrc,
    bf16* __restrict__ aggx, int N)
{
  const int t = threadIdx.x;
  const int lane = t & 63;
  const int q  = lane >> 4;    // node slot 0..3 in wave
  const int ql = lane & 15;    // 16B segment owner within row
  const int wid = (blockIdx.x * 256 + t) >> 6;
  const int nw = (gridDim.x * 256) >> 6;
  float sc[8], sh[8];
  if (use_act){
    *(float4*)(sc)   = *(const float4*)(bnp + ql*8);
    *(float4*)(sc+4) = *(const float4*)(bnp + ql*8 + 4);
    *(float4*)(sh)   = *(const float4*)(bnp + 128 + ql*8);
    *(float4*)(sh+4) = *(const float4*)(bnp + 128 + ql*8 + 4);
  }
  const int ngrp = N >> 2;   // N divisible by 4
  for (int p = wid; p < ngrp; p += nw){
    const int n = p*4 + q;
    const int start = rs[n];
    const int c = cnt[n];
    float a[8];
    #pragma unroll
    for (int j = 0; j < 8; ++j) a[j] = 0.f;
    int done = 0;
    while (done < c){
      int cc = min(c - done, 16);
      int my = (ql < cc) ? esrc[start + done + ql] : 0;
      int e = 0;
      for (; e + 4 <= cc; e += 4){
        int i0 = __shfl(my, q*16 + e);
        int i1 = __shfl(my, q*16 + e + 1);
        int i2 = __shfl(my, q*16 + e + 2);
        int i3 = __shfl(my, q*16 + e + 3);
        bf16x8 v0 = *(const bf16x8*)(hsrc + (size_t)i0*128 + ql*8);
        bf16x8 v1 = *(const bf16x8*)(hsrc + (size_t)i1*128 + ql*8);
        bf16x8 v2 = *(const bf16x8*)(hsrc + (size_t)i2*128 + ql*8);
        bf16x8 v3 = *(const bf16x8*)(hsrc + (size_t)i3*128 + ql*8);
        if (use_act){
          #pragma unroll
          for (int j = 0; j < 8; ++j){
            a[j] += fmaxf(fmaf((float)v0[j], sc[j], sh[j]), 0.f)
                  + fmaxf(fmaf((float)v1[j], sc[j], sh[j]), 0.f)
                  + fmaxf(fmaf((float)v2[j], sc[j], sh[j]), 0.f)
                  + fmaxf(fmaf((float)v3[j], sc[j], sh[j]), 0.f);
          }
        } else {
          #pragma unroll
          for (int j = 0; j < 8; ++j)
            a[j] += (float)v0[j] + (float)v1[j] + (float)v2[j] + (float)v3[j];
        }
      }
      for (; e < cc; ++e){
        int i0 = __shfl(my, q*16 + e);
        bf16x8 v0 = *(const bf16x8*)(hsrc + (size_t)i0*128 + ql*8);
        if (use_act){
          #pragma unroll
          for (int j = 0; j < 8; ++j)
            a[j] += fmaxf(fmaf((float)v0[j], sc[j], sh[j]), 0.f);
        } else {
          #pragma unroll
          for (int j = 0; j < 8; ++j) a[j] += (float)v0[j];
        }
      }
      done += cc;
    }
    float inv = 1.0f / (float)max(c, 1);
    bf16x8 o;
    #pragma unroll
    for (int j = 0; j < 8; ++j) o[j] = (bf16)(a[j] * inv);
    *(bf16x8*)(aggx + (size_t)n*128 + ql*8) = o;
  }
}

// ---------------- row-wave GEMM: h2 = [act(h)|aggx] @ [Wl;Wr]^T + bl + br(deg>0), L2-norm ----
// Wave owns 16 rows x 128 cols; W in per-lane-frag LDS (one sync); A frags from global;
// in-wave row norm (2 shfl); direct stores. No per-tile syncs.
__global__ __launch_bounds__(256, 2) void gemm_rowwave(
    const bf16* __restrict__ hin, const bf16* __restrict__ aggx,
    const float* __restrict__ bnp, int use_act,
    const bf16* __restrict__ Wbig, const float* __restrict__ bl, const float* __restrict__ br,
    const int* __restrict__ cnt, bf16* __restrict__ hout, int N)
{
  __shared__ bf16 wlds[64*64*8];   // 64 frags (nt*8+ks) x 64 lanes x 8 bf16 = 64 KB
  const int t = threadIdx.x;
  for (int g = t; g < 4096; g += 256){
    int c = g >> 5, kc = g & 31;
    int nt = c >> 4, l16c = c & 15, ks = kc >> 2, qd = kc & 3;
    bf16x8 v = *(const bf16x8*)(Wbig + (size_t)c*256 + kc*8);
    *(bf16x8*)(wlds + (((nt*8 + ks)*64) + qd*16 + l16c)*8) = v;
  }
  __syncthreads();   // only sync

  const int lane = t & 63;
  const int quad = lane >> 4, l16 = lane & 15;

  // act params for self k-chunks (cols ks*32+quad*8..+7, k<128)
  float sc[4][8], sh[4][8];
  if (use_act){
    #pragma unroll
    for (int ks = 0; ks < 4; ++ks){
      *(float4*)(sc[ks])   = *(const float4*)(bnp + ks*32 + quad*8);
      *(float4*)(sc[ks]+4) = *(const float4*)(bnp + ks*32 + quad*8 + 4);
      *(float4*)(sh[ks])   = *(const float4*)(bnp + 128 + ks*32 + quad*8);
      *(float4*)(sh[ks]+4) = *(const float4*)(bnp + 128 + ks*32 + quad*8 + 4);
    }
  }

  const int ntiles = N >> 4;   // N % 16 == 0
  const int gwave  = (blockIdx.x*256 + t) >> 6;
  const int nwaves = (gridDim.x*256) >> 6;
  for (int tile = gwave; tile < ntiles; tile += nwaves){
    const int row = (tile << 4) + l16;
    const int deg = cnt[row];
    // A frags: self (act) + agg (pre-act'd mean)
    bf16x8 selfv[4], aggv[4];
    #pragma unroll
    for (int ks = 0; ks < 4; ++ks){
      selfv[ks] = *(const bf16x8*)(hin  + (size_t)row*128 + ks*32 + quad*8);
      aggv[ks]  = *(const bf16x8*)(aggx + (size_t)row*128 + ks*32 + quad*8);
    }
    if (use_act){
      #pragma unroll
      for (int ks = 0; ks < 4; ++ks)
        #pragma unroll
        for (int j = 0; j < 8; ++j)
          selfv[ks][j] = (bf16)fmaxf(fmaf((float)selfv[ks][j], sc[ks][j], sh[ks][j]), 0.0f);
    }
    // MFMA: 8 n-tiles, K=256
    f32x4 acc[8];
    #pragma unroll
    for (int nt = 0; nt < 8; ++nt)
      #pragma unroll
      for (int r = 0; r < 4; ++r) acc[nt][r] = 0.f;
    #pragma unroll
    for (int ks = 0; ks < 8; ++ks){
      bf16x8 af = (ks < 4) ? selfv[ks] : aggv[ks - 4];
      #pragma unroll
      for (int nt = 0; nt < 8; ++nt){
        bf16x8 wf = *(const bf16x8*)(wlds + (((nt*8 + ks)*64) + lane)*8);
        acc[nt] = __builtin_amdgcn_mfma_f32_16x16x32_bf16(wf, af, acc[nt], 0, 0, 0);
      }
    }
    // epilogue: bias (+deg-0 fix), in-wave row L2-norm, store
    float rsq = 0.f;
    #pragma unroll
    for (int nt = 0; nt < 8; ++nt){
      float4 bl4 = *(const float4*)(bl + nt*16 + quad*4);
      float4 br4 = *(const float4*)(br + nt*16 + quad*4);
      acc[nt][0] += bl4.x + (deg ? br4.x : 0.f);
      acc[nt][1] += bl4.y + (deg ? br4.y : 0.f);
      acc[nt][2] += bl4.z + (deg ? br4.z : 0.f);
      acc[nt][3] += bl4.w + (deg ? br4.w : 0.f);
      rsq += acc[nt][0]*acc[nt][0] + acc[nt][1]*acc[nt][1]
           + acc[nt][2]*acc[nt][2] + acc[nt][3]*acc[nt][3];
    }
    rsq += __shfl_xor(rsq, 16);
    rsq += __shfl_xor(rsq, 32);
    const float scl = 1.0f / fmaxf(sqrtf(rsq), 1e-12f);
    #pragma unroll
    for (int nt = 0; nt < 8; ++nt){
      bf16x4 o;
      o[0] = (bf16)(acc[nt][0]*scl); o[1] = (bf16)(acc[nt][1]*scl);
      o[2] = (bf16)(acc[nt][2]*scl); o[3] = (bf16)(acc[nt][3]*scl);
      *(bf16x4*)(hout + (size_t)row*128 + nt*16 + quad*4) = o;
    }
  }
}

// ---------------- column stats of hout (coalesced): colstats += [colsum|colsq] ----------------
__global__ __launch_bounds__(256) void colstats_kernel(
    const bf16* __restrict__ h, float* __restrict__ colstats, int N)
{
  __shared__ float red[256][8];
  const int t = threadIdx.x;
  const int cg = t & 15;    // cols cg*8 .. +7
  const int rl = t >> 4;    // 16 row-lanes
  float s[8], q[8];
  #pragma unroll
  for (int j = 0; j < 8; ++j){ s[j] = 0.f; q[j] = 0.f; }
  for (int n = blockIdx.x*16 + rl; n < N; n += gridDim.x*16){
    bf16x8 v = *(const bf16x8*)(h + (size_t)n*128 + cg*8);
    #pragma unroll
    for (int j = 0; j < 8; ++j){
      float x = (float)v[j];
      s[j] += x; q[j] += x*x;
    }
  }
  #pragma unroll
  for (int j = 0; j < 8; ++j) red[t][j] = s[j];
  __syncthreads();
  if (t < 128){
    float a = 0.f;
    #pragma unroll
    for (int r = 0; r < 16; ++r) a += red[r*16 + (t>>3)][t & 7];
    atomicAdd(&colstats[t], a);
  }
  __syncthreads();
  #pragma unroll
  for (int j = 0; j < 8; ++j) red[t][j] = q[j];
  __syncthreads();
  if (t < 128){
    float a = 0.f;
    #pragma unroll
    for (int r = 0; r < 16; ++r) a += red[r*16 + (t>>3)][t & 7];
    atomicAdd(&colstats[128 + t], a);
  }
}

// ---------------- BN params; zero stats for next layer ----------------
__global__ void bn_params_kernel(float* __restrict__ cs, const float* __restrict__ gamma,
                                 const float* __restrict__ beta, float* __restrict__ bnp, float Nf){
  int t = threadIdx.x;   // 0..127
  float sum = cs[t], sq = cs[128 + t];
  float mu  = sum / Nf;
  float var = fmaxf(sq / Nf - mu*mu, 0.0f);
  float inv = rsqrtf(var + 1e-5f);
  float scale = gamma[t] * inv;
  bnp[t] = scale;
  bnp[128 + t] = beta[t] - mu * scale;
  cs[t] = 0.0f; cs[128 + t] = 0.0f;
}

// ---------------- pool act(h) per graph ----------------
__global__ __launch_bounds__(256) void poolh_kernel(
    const bf16* __restrict__ h, const float* __restrict__ bnp,
    const int* __restrict__ batch, float* __restrict__ pooledh, int N)
{
  const int t = threadIdx.x;
  const int col = t & 127;
  const int half = t >> 7;
  const float sc = bnp[col];
  const float sh = bnp[128 + col];
  const int chunk = (N + gridDim.x - 1) / gridDim.x;
  const int lo = blockIdx.x * chunk;
  const int hi = min(N, lo + chunk);
  if (lo >= hi) return;
  int gcur = -1;
  float acc = 0.f;
  for (int n = lo + half; n < hi; n += 2){
    int g = batch[n];
    if (g != gcur){
      if (gcur >= 0) atomicAdd(&pooledh[gcur*128 + col], acc);
      gcur = g; acc = 0.f;
    }
    float v = (float)h[(size_t)n*128 + col];
    acc += fmaxf(fmaf(v, sc, sh), 0.f);
  }
  if (gcur >= 0) atomicAdd(&pooledh[gcur*128 + col], acc);
}

// ---------------- final: out[g] = log_softmax(pooledh[g] @ Wc^T + cnt_g*bc) ----------------
__global__ void lsm_kernel(const float* __restrict__ ph, const float* __restrict__ Wc,
                           const float* __restrict__ bc, const int* __restrict__ batch,
                           int N, float* __restrict__ out)
{
  __shared__ int cntg_s;
  const int g = blockIdx.x;
  const int t = threadIdx.x;   // 64 threads = one wave
  if (t == 0){
    int lo = 0, hi = N;
    while (lo < hi){ int mid = (lo + hi) >> 1; if (batch[mid] < g) lo = mid + 1; else hi = mid; }
    int lo2 = lo, hi2 = N;
    while (lo2 < hi2){ int mid = (lo2 + hi2) >> 1; if (batch[mid] < g + 1) lo2 = mid + 1; else hi2 = mid; }
    cntg_s = lo2 - lo;
  }
  __syncthreads();
  float z = -3.0e38f;
  if (t < 40){
    float s = (float)cntg_s * bc[t];
    const float* phg = ph + g*128;
    const float* w = Wc + t*128;
    for (int k = 0; k < 128; k += 4){
      float4 a = *(const float4*)(phg + k);
      float4 b = *(const float4*)(w + k);
      s = fmaf(a.x, b.x, s); s = fmaf(a.y, b.y, s);
      s = fmaf(a.z, b.z, s); s = fmaf(a.w, b.w, s);
    }
    z = s;
  }
  float mx = z;
  #pragma unroll
  for (int off = 32; off; off >>= 1) mx = fmaxf(mx, __shfl_xor(mx, off));
  float ex = (t < 40) ? expf(z - mx) : 0.0f;
  float sum = ex;
  #pragma unroll
  for (int off = 32; off; off >>= 1) sum += __shfl_xor(sum, off);
  float lse = mx + logf(sum);
  if (t < 40) out[g*40 + t] = z - lse;
}

extern "C" void kernel_launch(void* const* d_in, const int* in_sizes, int n_in,
                              void* d_out, int out_size, void* d_ws, size_t ws_size,
                              hipStream_t stream)
{
  const float* x    = (const float*)d_in[0];
  const int*   ei   = (const int*)d_in[1];
  const int*   batch= (const int*)d_in[2];
  const float* Wl   = (const float*)d_in[3];
  const float* bl   = (const float*)d_in[4];
  const float* Wr   = (const float*)d_in[5];
  const float* br   = (const float*)d_in[6];
  const float* gamma= (const float*)d_in[7];
  const float* beta = (const float*)d_in[8];
  const float* W1   = (const float*)d_in[9];
  const float* b1   = (const float*)d_in[10];
  const float* W2   = (const float*)d_in[11];
  const float* b2   = (const float*)d_in[12];
  float* out = (float*)d_out;

  const int N = in_sizes[0] / 128;
  const int E = in_sizes[1] / 2;
  const int G = out_size / 40;

  char* p = (char*)d_ws;
  auto carve = [&](size_t bytes)->char*{ char* r = p; p += alignup(bytes); return r; };
  bf16*  xbf      = (bf16*)carve((size_t)N * 128 * 2);
  bf16*  aggx     = (bf16*)carve((size_t)N * 128 * 2);
  bf16*  hA       = (bf16*)carve((size_t)N * 128 * 2);
  bf16*  hB       = (bf16*)carve((size_t)N * 128 * 2);
  int*   esrc     = (int*)carve((size_t)E * 4);
  int*   rs       = (int*)carve((size_t)N * 4);
  int*   cnt      = (int*)carve((size_t)N * 4);
  int*   cur      = (int*)carve((size_t)N * 4);
  int*   bsum     = (int*)carve(512 * 4);
  float* colstats = (float*)carve(256 * 4);
  float* bnp      = (float*)carve(256 * 4);
  float* Wc       = (float*)carve(40 * 128 * 4);
  float* bc       = (float*)carve(40 * 4);
  bf16*  Wbig     = (bf16*)carve((size_t)3 * 128 * 256 * 2);
  float* pooledh  = (float*)carve((size_t)G * 128 * 4);

  hipMemsetAsync(cnt, 0, (size_t)N * 4, stream);
  hipMemsetAsync(colstats, 0, 256 * 4, stream);
  hipMemsetAsync(pooledh, 0, (size_t)G * 128 * 4, stream);

  const int eb = (E + 255) / 256;
  const int nb = (N + 255) / 256;
  count_kernel<<<eb, 256, 0, stream>>>(ei, E, cnt);
  scan1_kernel<<<nb, 256, 0, stream>>>(cnt, rs, bsum, N);
  scan2_kernel<<<1, 512, 0, stream>>>(bsum, nb);
  scan3_kernel<<<nb, 256, 0, stream>>>(rs, bsum, cur, N);
  fill_kernel<<<eb, 256, 0, stream>>>(ei, E, cur, esrc);
  xbf_kernel<<<(N*16 + 255)/256, 256, 0, stream>>>(x, xbf, N*16);
  wc_kernel<<<40, 128, 0, stream>>>(W1, b1, W2, b2, Wc, bc);
  wprep_kernel<<<(3*128*256 + 255)/256, 256, 0, stream>>>(Wl, Wr, Wbig);

  const float Nf = (float)N;
  // ping-pong: l0 xbf->hA, l1 hA->hB, l2 hB->hA  (hin never aliases hout)
  const bf16* ins[3]  = {xbf, hA, hB};
  bf16*       outs[3] = {hA,  hB, hA};
  for (int l = 0; l < 3; ++l){
    gather_kernel<<<4096, 256, 0, stream>>>(ins[l], bnp, (l > 0) ? 1 : 0,
                                            rs, cnt, esrc, aggx, N);
    gemm_rowwave<<<512, 256, 0, stream>>>(ins[l], aggx, bnp, (l > 0) ? 1 : 0,
                                          Wbig + (size_t)l * 32768, bl + l*128, br + l*128,
                                          cnt, outs[l], N);
    colstats_kernel<<<256, 256, 0, stream>>>(outs[l], colstats, N);
    bn_params_kernel<<<1, 128, 0, stream>>>(colstats, gamma + l*128, beta + l*128, bnp, Nf);
  }
  poolh_kernel<<<1024, 256, 0, stream>>>(hA, bnp, batch, pooledh, N);
  lsm_kernel<<<G, 64, 0, stream>>>(pooledh, Wc, bc, batch, N, out);
}

// Round 9
// 659.329 us; speedup vs baseline: 1.6700x; 1.0371x over previous
//
#include <hip/hip_runtime.h>
#include <math.h>

// GraphSage GNN forward. N=100000 (div 16), E=600000, HID=128, OUT=40, G=64, L=3.
// R9: barrier-free row-wave GEMM with wave-private LDS bounce for A-loads and C-stores
// (all global traffic lane-adjacent coalesced -> no sector amplification), W read from
// global in frag-linear layout (L1/L2-hot). Separate gather (R4 shape). Lessons:
// R7: random gather + partial stores in one kernel -> L2 thrash, 10x write amp.
// R8: scattered-lane (quad,l16) global addressing -> 4x sector amplification.

typedef __bf16 bf16;
typedef __bf16 bf16x4 __attribute__((ext_vector_type(4)));
typedef __bf16 bf16x8 __attribute__((ext_vector_type(8)));
typedef float  f32x4  __attribute__((ext_vector_type(4)));

static inline size_t alignup(size_t x){ return (x + 255) & ~(size_t)255; }

// ---------------- CSR build ----------------
__global__ void count_kernel(const int* __restrict__ ei, int E, int* __restrict__ cnt){
  int e = blockIdx.x*256 + threadIdx.x;
  if (e < E) atomicAdd(&cnt[ei[E + e]], 1);   // dst row
}

__global__ void scan1_kernel(const int* __restrict__ cnt, int* __restrict__ rs,
                             int* __restrict__ bsum, int N){
  __shared__ int s[256];
  int t = threadIdx.x;
  int i = blockIdx.x*256 + t;
  int v = (i < N) ? cnt[i] : 0;
  s[t] = v; __syncthreads();
  for (int off = 1; off < 256; off <<= 1){
    int x = (t >= off) ? s[t-off] : 0;
    __syncthreads();
    s[t] += x;
    __syncthreads();
  }
  if (i < N) rs[i] = s[t] - v;
  if (t == 255) bsum[blockIdx.x] = s[255];
}

__global__ void scan2_kernel(int* __restrict__ bsum, int NB){
  __shared__ int s[512];
  int t = threadIdx.x;
  int v = (t < NB) ? bsum[t] : 0;
  s[t] = v; __syncthreads();
  for (int off = 1; off < 512; off <<= 1){
    int x = (t >= off) ? s[t-off] : 0;
    __syncthreads();
    s[t] += x;
    __syncthreads();
  }
  if (t < NB) bsum[t] = s[t] - v;
}

__global__ void scan3_kernel(int* __restrict__ rs, const int* __restrict__ bsum,
                             int* __restrict__ cur, int N){
  int i = blockIdx.x*256 + threadIdx.x;
  if (i < N){
    int v = rs[i] + bsum[blockIdx.x];
    rs[i] = v;
    cur[i] = v;
  }
}

__global__ void fill_kernel(const int* __restrict__ ei, int E, int* __restrict__ cur,
                            int* __restrict__ esrc){
  int e = blockIdx.x*256 + threadIdx.x;
  if (e < E){
    int d = ei[E + e];
    int p = atomicAdd(&cur[d], 1);
    esrc[p] = ei[e];
  }
}

// ---------------- x -> bf16 ----------------
__global__ void xbf_kernel(const float* __restrict__ x, bf16* __restrict__ xb, int total8){
  int i = blockIdx.x*256 + threadIdx.x;
  if (i < total8){
    float4 a = *(const float4*)(x + (size_t)i*8);
    float4 b = *(const float4*)(x + (size_t)i*8 + 4);
    bf16x8 o;
    o[0]=(bf16)a.x; o[1]=(bf16)a.y; o[2]=(bf16)a.z; o[3]=(bf16)a.w;
    o[4]=(bf16)b.x; o[5]=(bf16)b.y; o[6]=(bf16)b.z; o[7]=(bf16)b.w;
    *(bf16x8*)(xb + (size_t)i*8) = o;
  }
}

// ---------------- collapsed postMP weights: Wc = W2@W1 (40x128), bc = W2@b1 + b2 ----------------
__global__ void wc_kernel(const float* __restrict__ W1, const float* __restrict__ b1,
                          const float* __restrict__ W2, const float* __restrict__ b2,
                          float* __restrict__ Wc, float* __restrict__ bc){
  int o = blockIdx.x;        // 0..39
  int k = threadIdx.x;       // 0..127
  float s = 0.0f;
  for (int j = 0; j < 128; ++j) s = fmaf(W2[o*128 + j], W1[j*128 + k], s);
  Wc[o*128 + k] = s;
  __shared__ float r[128];
  r[k] = W2[o*128 + k] * b1[k];
  __syncthreads();
  for (int off = 64; off; off >>= 1){
    if (k < off) r[k] += r[k + off];
    __syncthreads();
  }
  if (k == 0) bc[o] = r[0] + b2[o];
}

// ---------------- weight prep: frag-linear layout for direct global reads ----------------
// Wfrag[l][(nt*8+ks)*64 + lane] (bf16x8 unit) = W[col = nt*16+(lane&15)][k = ks*32+(lane>>4)*8 ..+7]
// where W = [Wl ; Wr] along k (k<128 -> Wl, else Wr), per layer l.
__global__ void wprep_kernel(const float* __restrict__ Wl, const float* __restrict__ Wr,
                             bf16* __restrict__ Wfrag){
  int idx = blockIdx.x*256 + threadIdx.x;   // 3*4096
  if (idx < 3*4096){
    int l = idx >> 12, rem = idx & 4095;
    int lane = rem & 63, fr = rem >> 6;      // fr = nt*8 + ks
    int nt = fr >> 3, ks = fr & 7;
    int col = nt*16 + (lane & 15);
    int kbase = ks*32 + (lane >> 4)*8;
    bf16x8 o;
    #pragma unroll
    for (int j = 0; j < 8; ++j){
      int k = kbase + j;
      float w = (k < 128) ? Wl[l*16384 + col*128 + k]
                          : Wr[l*16384 + col*128 + (k - 128)];
      o[j] = (bf16)w;
    }
    *(bf16x8*)(Wfrag + (size_t)idx*8) = o;
  }
}

// ---------------- gather: aggx[n] = mean_{j in N(n)} act(h[j]) (R4's measured-best shape) ----
__global__ __launch_bounds__(256) void gather_kernel(
    const bf16* __restrict__ hsrc, const float* __restrict__ bnp, int use_act,
    const int* __restrict__ rs, const int* __restrict__ cnt, const int* __restrict__ esrc,
    bf16* __restrict__ aggx, int N)
{
  const int t = threadIdx.x;
  const int lane = t & 63;
  const int q  = lane >> 4;    // node slot 0..3 in wave
  const int ql = lane & 15;    // 16B segment owner within row
  const int wid = (blockIdx.x * 256 + t) >> 6;
  const int nw = (gridDim.x * 256) >> 6;
  float sc[8], sh[8];
  if (use_act){
    *(float4*)(sc)   = *(const float4*)(bnp + ql*8);
    *(float4*)(sc+4) = *(const float4*)(bnp + ql*8 + 4);
    *(float4*)(sh)   = *(const float4*)(bnp + 128 + ql*8);
    *(float4*)(sh+4) = *(const float4*)(bnp + 128 + ql*8 + 4);
  }
  const int ngrp = N >> 2;   // N divisible by 4
  for (int p = wid; p < ngrp; p += nw){
    const int n = p*4 + q;
    const int start = rs[n];
    const int c = cnt[n];
    float a[8];
    #pragma unroll
    for (int j = 0; j < 8; ++j) a[j] = 0.f;
    int done = 0;
    while (done < c){
      int cc = min(c - done, 16);
      int my = (ql < cc) ? esrc[start + done + ql] : 0;
      int e = 0;
      for (; e + 4 <= cc; e += 4){
        int i0 = __shfl(my, q*16 + e);
        int i1 = __shfl(my, q*16 + e + 1);
        int i2 = __shfl(my, q*16 + e + 2);
        int i3 = __shfl(my, q*16 + e + 3);
        bf16x8 v0 = *(const bf16x8*)(hsrc + (size_t)i0*128 + ql*8);
        bf16x8 v1 = *(const bf16x8*)(hsrc + (size_t)i1*128 + ql*8);
        bf16x8 v2 = *(const bf16x8*)(hsrc + (size_t)i2*128 + ql*8);
        bf16x8 v3 = *(const bf16x8*)(hsrc + (size_t)i3*128 + ql*8);
        if (use_act){
          #pragma unroll
          for (int j = 0; j < 8; ++j){
            a[j] += fmaxf(fmaf((float)v0[j], sc[j], sh[j]), 0.f)
                  + fmaxf(fmaf((float)v1[j], sc[j], sh[j]), 0.f)
                  + fmaxf(fmaf((float)v2[j], sc[j], sh[j]), 0.f)
                  + fmaxf(fmaf((float)v3[j], sc[j], sh[j]), 0.f);
          }
        } else {
          #pragma unroll
          for (int j = 0; j < 8; ++j)
            a[j] += (float)v0[j] + (float)v1[j] + (float)v2[j] + (float)v3[j];
        }
      }
      for (; e < cc; ++e){
        int i0 = __shfl(my, q*16 + e);
        bf16x8 v0 = *(const bf16x8*)(hsrc + (size_t)i0*128 + ql*8);
        if (use_act){
          #pragma unroll
          for (int j = 0; j < 8; ++j)
            a[j] += fmaxf(fmaf((float)v0[j], sc[j], sh[j]), 0.f);
        } else {
          #pragma unroll
          for (int j = 0; j < 8; ++j) a[j] += (float)v0[j];
        }
      }
      done += cc;
    }
    float inv = 1.0f / (float)max(c, 1);
    bf16x8 o;
    #pragma unroll
    for (int j = 0; j < 8; ++j) o[j] = (bf16)(a[j] * inv);
    *(bf16x8*)(aggx + (size_t)n*128 + ql*8) = o;
  }
}

// ---------------- barrier-free row-wave GEMM with wave-private LDS bounce ----------------
// Wave owns 16 rows x 128 cols. A = [act(h)|aggx] (16x256) copied coalesced global->LDS
// (XOR-swizzled 16B chunks: phys = c ^ (row&7)); frag ds_read_b128 conflict-free.
// W read per-MFMA from global frag-linear layout (lane-adjacent, L1/L2-hot).
// C frags -> LDS (unit swizzle u^= (l16&7)<<2) -> coalesced 1KB global stores. No syncs.
__global__ __launch_bounds__(256, 2) void gemm_rowwave(
    const bf16* __restrict__ hin, const bf16* __restrict__ aggx,
    const float* __restrict__ bnp, int use_act,
    const bf16* __restrict__ Wfrag, const float* __restrict__ bl, const float* __restrict__ br,
    const int* __restrict__ cnt, bf16* __restrict__ hout, int N)
{
  __shared__ bf16 ascr_all[4][4096];   // 8 KB per wave
  const int t = threadIdx.x;
  const int wv = t >> 6, lane = t & 63;
  const int quad = lane >> 4, l16 = lane & 15;
  bf16* ascr = ascr_all[wv];

  // bias preload: col = nt*16 + quad*4 + r
  float biasv[8][4], brv[8][4];
  #pragma unroll
  for (int nt = 0; nt < 8; ++nt){
    float4 b4 = *(const float4*)(bl + nt*16 + quad*4);
    float4 r4 = *(const float4*)(br + nt*16 + quad*4);
    biasv[nt][0] = b4.x + r4.x; biasv[nt][1] = b4.y + r4.y;
    biasv[nt][2] = b4.z + r4.z; biasv[nt][3] = b4.w + r4.w;
    brv[nt][0] = r4.x; brv[nt][1] = r4.y; brv[nt][2] = r4.z; brv[nt][3] = r4.w;
  }
  // act params for copy lanes: cols (lane&15)*8 .. +7
  float sca[8], sha[8];
  if (use_act){
    *(float4*)(sca)   = *(const float4*)(bnp + (lane & 15)*8);
    *(float4*)(sca+4) = *(const float4*)(bnp + (lane & 15)*8 + 4);
    *(float4*)(sha)   = *(const float4*)(bnp + 128 + (lane & 15)*8);
    *(float4*)(sha+4) = *(const float4*)(bnp + 128 + (lane & 15)*8 + 4);
  }

  const int ntiles = N >> 4;               // N % 16 == 0
  const int nwaves = gridDim.x * 4;
  for (int tile = blockIdx.x*4 + wv; tile < ntiles; tile += nwaves){
    const size_t base = (size_t)tile * (16*128);
    // ---- copy-in: fully coalesced 1KB loads, swizzled LDS writes ----
    #pragma unroll
    for (int j = 0; j < 4; ++j){
      const int row = j*4 + (lane >> 4);
      const int c   = lane & 15;
      const int phys = (c ^ (row & 7));
      bf16x8 v = *(const bf16x8*)(hin + base + j*512 + lane*8);
      if (use_act){
        #pragma unroll
        for (int q2 = 0; q2 < 8; ++q2)
          v[q2] = (bf16)fmaxf(fmaf((float)v[q2], sca[q2], sha[q2]), 0.0f);
      }
      *(bf16x8*)(ascr + row*256 + phys*8) = v;
      bf16x8 u = *(const bf16x8*)(aggx + base + j*512 + lane*8);
      *(bf16x8*)(ascr + row*256 + (16 + phys)*8) = u;
    }
    const int deg = cnt[(tile << 4) + l16];
    // ---- MFMA: K=256, 8 n-tiles; af from swizzled LDS, wf from global frag layout ----
    f32x4 acc[8];
    #pragma unroll
    for (int nt = 0; nt < 8; ++nt)
      #pragma unroll
      for (int r = 0; r < 4; ++r) acc[nt][r] = 0.f;
    #pragma unroll
    for (int ks = 0; ks < 8; ++ks){
      bf16x8 af = *(const bf16x8*)(ascr + l16*256 + (((ks*4 + quad) ^ (l16 & 7)))*8);
      #pragma unroll
      for (int nt = 0; nt < 8; ++nt){
        bf16x8 wf = *(const bf16x8*)(Wfrag + (size_t)((nt*8 + ks)*64 + lane)*8);
        acc[nt] = __builtin_amdgcn_mfma_f32_16x16x32_bf16(wf, af, acc[nt], 0, 0, 0);
      }
    }
    // ---- epilogue: bias (+deg-0 fix), in-wave row L2-norm ----
    float rsq = 0.f;
    #pragma unroll
    for (int nt = 0; nt < 8; ++nt){
      #pragma unroll
      for (int r = 0; r < 4; ++r){
        float b = biasv[nt][r] - (deg ? 0.f : brv[nt][r]);
        acc[nt][r] += b;
        rsq += acc[nt][r]*acc[nt][r];
      }
    }
    rsq += __shfl_xor(rsq, 16);
    rsq += __shfl_xor(rsq, 32);
    const float scl = 1.0f / fmaxf(sqrtf(rsq), 1e-12f);
    // ---- C bounce: swizzled b64 LDS writes (conflict-free), coalesced 1KB stores ----
    #pragma unroll
    for (int nt = 0; nt < 8; ++nt){
      bf16x4 o;
      o[0] = (bf16)(acc[nt][0]*scl); o[1] = (bf16)(acc[nt][1]*scl);
      o[2] = (bf16)(acc[nt][2]*scl); o[3] = (bf16)(acc[nt][3]*scl);
      const int u = (nt*4 + quad) ^ ((l16 & 7) << 2);
      *(bf16x4*)(ascr + l16*128 + u*4) = o;
    }
    #pragma unroll
    for (int j = 0; j < 4; ++j){
      const int row = j*4 + (lane >> 4);
      const int c16 = lane & 15;
      const int up = (2*c16) ^ ((row & 7) << 2);
      bf16x8 v = *(const bf16x8*)(ascr + row*128 + up*4);
      *(bf16x8*)(hout + base + j*512 + lane*8) = v;
    }
  }
}

// ---------------- column stats of hout (coalesced): colstats += [colsum|colsq] ----------------
__global__ __launch_bounds__(256) void colstats_kernel(
    const bf16* __restrict__ h, float* __restrict__ colstats, int N)
{
  __shared__ float red[256][8];
  const int t = threadIdx.x;
  const int cg = t & 15;    // cols cg*8 .. +7
  const int rl = t >> 4;    // 16 row-lanes
  float s[8], q[8];
  #pragma unroll
  for (int j = 0; j < 8; ++j){ s[j] = 0.f; q[j] = 0.f; }
  for (int n = blockIdx.x*16 + rl; n < N; n += gridDim.x*16){
    bf16x8 v = *(const bf16x8*)(h + (size_t)n*128 + cg*8);
    #pragma unroll
    for (int j = 0; j < 8; ++j){
      float x = (float)v[j];
      s[j] += x; q[j] += x*x;
    }
  }
  #pragma unroll
  for (int j = 0; j < 8; ++j) red[t][j] = s[j];
  __syncthreads();
  if (t < 128){
    float a = 0.f;
    #pragma unroll
    for (int r = 0; r < 16; ++r) a += red[r*16 + (t>>3)][t & 7];
    atomicAdd(&colstats[t], a);
  }
  __syncthreads();
  #pragma unroll
  for (int j = 0; j < 8; ++j) red[t][j] = q[j];
  __syncthreads();
  if (t < 128){
    float a = 0.f;
    #pragma unroll
    for (int r = 0; r < 16; ++r) a += red[r*16 + (t>>3)][t & 7];
    atomicAdd(&colstats[128 + t], a);
  }
}

// ---------------- BN params; zero stats for next layer ----------------
__global__ void bn_params_kernel(float* __restrict__ cs, const float* __restrict__ gamma,
                                 const float* __restrict__ beta, float* __restrict__ bnp, float Nf){
  int t = threadIdx.x;   // 0..127
  float sum = cs[t], sq = cs[128 + t];
  float mu  = sum / Nf;
  float var = fmaxf(sq / Nf - mu*mu, 0.0f);
  float inv = rsqrtf(var + 1e-5f);
  float scale = gamma[t] * inv;
  bnp[t] = scale;
  bnp[128 + t] = beta[t] - mu * scale;
  cs[t] = 0.0f; cs[128 + t] = 0.0f;
}

// ---------------- pool act(h) per graph ----------------
__global__ __launch_bounds__(256) void poolh_kernel(
    const bf16* __restrict__ h, const float* __restrict__ bnp,
    const int* __restrict__ batch, float* __restrict__ pooledh, int N)
{
  const int t = threadIdx.x;
  const int col = t & 127;
  const int half = t >> 7;
  const float sc = bnp[col];
  const float sh = bnp[128 + col];
  const int chunk = (N + gridDim.x - 1) / gridDim.x;
  const int lo = blockIdx.x * chunk;
  const int hi = min(N, lo + chunk);
  if (lo >= hi) return;
  int gcur = -1;
  float acc = 0.f;
  for (int n = lo + half; n < hi; n += 2){
    int g = batch[n];
    if (g != gcur){
      if (gcur >= 0) atomicAdd(&pooledh[gcur*128 + col], acc);
      gcur = g; acc = 0.f;
    }
    float v = (float)h[(size_t)n*128 + col];
    acc += fmaxf(fmaf(v, sc, sh), 0.f);
  }
  if (gcur >= 0) atomicAdd(&pooledh[gcur*128 + col], acc);
}

// ---------------- final: out[g] = log_softmax(pooledh[g] @ Wc^T + cnt_g*bc) ----------------
__global__ void lsm_kernel(const float* __restrict__ ph, const float* __restrict__ Wc,
                           const float* __restrict__ bc, const int* __restrict__ batch,
                           int N, float* __restrict__ out)
{
  __shared__ int cntg_s;
  const int g = blockIdx.x;
  const int t = threadIdx.x;   // 64 threads = one wave
  if (t == 0){
    int lo = 0, hi = N;
    while (lo < hi){ int mid = (lo + hi) >> 1; if (batch[mid] < g) lo = mid + 1; else hi = mid; }
    int lo2 = lo, hi2 = N;
    while (lo2 < hi2){ int mid = (lo2 + hi2) >> 1; if (batch[mid] < g + 1) lo2 = mid + 1; else hi2 = mid; }
    cntg_s = lo2 - lo;
  }
  __syncthreads();
  float z = -3.0e38f;
  if (t < 40){
    float s = (float)cntg_s * bc[t];
    const float* phg = ph + g*128;
    const float* w = Wc + t*128;
    for (int k = 0; k < 128; k += 4){
      float4 a = *(const float4*)(phg + k);
      float4 b = *(const float4*)(w + k);
      s = fmaf(a.x, b.x, s); s = fmaf(a.y, b.y, s);
      s = fmaf(a.z, b.z, s); s = fmaf(a.w, b.w, s);
    }
    z = s;
  }
  float mx = z;
  #pragma unroll
  for (int off = 32; off; off >>= 1) mx = fmaxf(mx, __shfl_xor(mx, off));
  float ex = (t < 40) ? expf(z - mx) : 0.0f;
  float sum = ex;
  #pragma unroll
  for (int off = 32; off; off >>= 1) sum += __shfl_xor(sum, off);
  float lse = mx + logf(sum);
  if (t < 40) out[g*40 + t] = z - lse;
}

extern "C" void kernel_launch(void* const* d_in, const int* in_sizes, int n_in,
                              void* d_out, int out_size, void* d_ws, size_t ws_size,
                              hipStream_t stream)
{
  const float* x    = (const float*)d_in[0];
  const int*   ei   = (const int*)d_in[1];
  const int*   batch= (const int*)d_in[2];
  const float* Wl   = (const float*)d_in[3];
  const float* bl   = (const float*)d_in[4];
  const float* Wr   = (const float*)d_in[5];
  const float* br   = (const float*)d_in[6];
  const float* gamma= (const float*)d_in[7];
  const float* beta = (const float*)d_in[8];
  const float* W1   = (const float*)d_in[9];
  const float* b1   = (const float*)d_in[10];
  const float* W2   = (const float*)d_in[11];
  const float* b2   = (const float*)d_in[12];
  float* out = (float*)d_out;

  const int N = in_sizes[0] / 128;
  const int E = in_sizes[1] / 2;
  const int G = out_size / 40;

  char* p = (char*)d_ws;
  auto carve = [&](size_t bytes)->char*{ char* r = p; p += alignup(bytes); return r; };
  bf16*  xbf      = (bf16*)carve((size_t)N * 128 * 2);
  bf16*  aggx     = (bf16*)carve((size_t)N * 128 * 2);
  bf16*  hA       = (bf16*)carve((size_t)N * 128 * 2);
  bf16*  hB       = (bf16*)carve((size_t)N * 128 * 2);
  int*   esrc     = (int*)carve((size_t)E * 4);
  int*   rs       = (int*)carve((size_t)N * 4);
  int*   cnt      = (int*)carve((size_t)N * 4);
  int*   cur      = (int*)carve((size_t)N * 4);
  int*   bsum     = (int*)carve(512 * 4);
  float* colstats = (float*)carve(256 * 4);
  float* bnp      = (float*)carve(256 * 4);
  float* Wc       = (float*)carve(40 * 128 * 4);
  float* bc       = (float*)carve(40 * 4);
  bf16*  Wfrag    = (bf16*)carve((size_t)3 * 4096 * 8 * 2);
  float* pooledh  = (float*)carve((size_t)G * 128 * 4);

  hipMemsetAsync(cnt, 0, (size_t)N * 4, stream);
  hipMemsetAsync(colstats, 0, 256 * 4, stream);
  hipMemsetAsync(pooledh, 0, (size_t)G * 128 * 4, stream);

  const int eb = (E + 255) / 256;
  const int nb = (N + 255) / 256;
  count_kernel<<<eb, 256, 0, stream>>>(ei, E, cnt);
  scan1_kernel<<<nb, 256, 0, stream>>>(cnt, rs, bsum, N);
  scan2_kernel<<<1, 512, 0, stream>>>(bsum, nb);
  scan3_kernel<<<nb, 256, 0, stream>>>(rs, bsum, cur, N);
  fill_kernel<<<eb, 256, 0, stream>>>(ei, E, cur, esrc);
  xbf_kernel<<<(N*16 + 255)/256, 256, 0, stream>>>(x, xbf, N*16);
  wc_kernel<<<40, 128, 0, stream>>>(W1, b1, W2, b2, Wc, bc);
  wprep_kernel<<<(3*4096 + 255)/256, 256, 0, stream>>>(Wl, Wr, Wfrag);

  const float Nf = (float)N;
  // ping-pong: l0 xbf->hA, l1 hA->hB, l2 hB->hA  (hin never aliases hout)
  const bf16* ins[3]  = {xbf, hA, hB};
  bf16*       outs[3] = {hA,  hB, hA};
  for (int l = 0; l < 3; ++l){
    gather_kernel<<<4096, 256, 0, stream>>>(ins[l], bnp, (l > 0) ? 1 : 0,
                                            rs, cnt, esrc, aggx, N);
    gemm_rowwave<<<512, 256, 0, stream>>>(ins[l], aggx, bnp, (l > 0) ? 1 : 0,
                                          Wfrag + (size_t)l * 32768, bl + l*128, br + l*128,
                                          cnt, outs[l], N);
    colstats_kernel<<<256, 256, 0, stream>>>(outs[l], colstats, N);
    bn_params_kernel<<<1, 128, 0, stream>>>(colstats, gamma + l*128, beta + l*128, bnp, Nf);
  }
  poolh_kernel<<<1024, 256, 0, stream>>>(hA, bnp, batch, pooledh, N);
  lsm_kernel<<<G, 64, 0, stream>>>(pooledh, Wc, bc, batch, N, out);
}